// Round 5
// baseline (342.807 us; speedup 1.0000x reference)
//
#include <hip/hip_runtime.h>
#include <hip/hip_bf16.h>

#define BQ   16
#define BK2  32     // 2B
#define SEQ  256
#define HD   768

typedef __attribute__((ext_vector_type(8))) short bf16x8;
typedef __attribute__((ext_vector_type(4))) float f32x4;

__device__ __forceinline__ void glds16(const unsigned short* g, unsigned short* l) {
    __builtin_amdgcn_global_load_lds(
        (const __attribute__((address_space(1))) unsigned int*)g,
        (__attribute__((address_space(3))) unsigned int*)l, 16, 0, 0);
}

// branch-free RNE fp32->bf16, packed two at a time
__device__ __forceinline__ unsigned int pack2_bf16(float a, float b) {
    unsigned ua = __float_as_uint(a), ub = __float_as_uint(b);
    ua += 0x7FFFu + ((ua >> 16) & 1u);
    ub += 0x7FFFu + ((ub >> 16) & 1u);
    return (ua >> 16) | (ub & 0xFFFF0000u);
}

// ---------------- Phase 1: fp32 l2-normalize -> bf16 (+ zero li counters) --
__global__ __launch_bounds__(256) void norm_kernel(
    const float* __restrict__ q, const float* __restrict__ k,
    unsigned short* __restrict__ qn, unsigned short* __restrict__ kn,
    int* __restrict__ cnt)
{
    if (blockIdx.x == 0 && threadIdx.x < 256) {      // zero 512 pair-counters
        cnt[threadIdx.x] = 0; cnt[threadIdx.x + 256] = 0;
    }
    int row  = blockIdx.x * 4 + (threadIdx.x >> 6);
    int lane = threadIdx.x & 63;
    const int NQ = BQ * SEQ;
    const float* src = (row < NQ) ? q + (size_t)row * HD
                                  : k + (size_t)(row - NQ) * HD;
    unsigned int* dst = (unsigned int*)((row < NQ) ? qn + (size_t)row * HD
                                                   : kn + (size_t)(row - NQ) * HD);
    float4 v[3];
    float ss = 0.f;
#pragma unroll
    for (int c = 0; c < 3; ++c) {
        v[c] = ((const float4*)src)[lane + 64 * c];
        ss += v[c].x * v[c].x + v[c].y * v[c].y + v[c].z * v[c].z + v[c].w * v[c].w;
    }
#pragma unroll
    for (int m = 1; m < 64; m <<= 1) ss += __shfl_xor(ss, m, 64);
    float inv = rsqrtf(fmaxf(ss, 1e-24f));
#pragma unroll
    for (int c = 0; c < 3; ++c) {
        uint2 o = make_uint2(pack2_bf16(v[c].x * inv, v[c].y * inv),
                             pack2_bf16(v[c].z * inv, v[c].w * inv));
        ((uint2*)dst)[lane + 64 * c] = o;
    }
}

// ---------------- Phase 2: block = (j, i, sh|th) covering 128 s x 128 t ----
// R2's proven shape: 4 waves as 2x2 of 64x64 MFMA tiles, glds staging,
// swizzled LDS (pitch 64). Block writes per-row (Z,W) partials to pw; the
// last of the 4 blocks per (i,j) finishes softmax + reduction inline.
__global__ __launch_bounds__(256, 4) void li_kernel(
    const unsigned short* __restrict__ qn, const unsigned short* __restrict__ kn,
    const float* __restrict__ g_ls, const float* __restrict__ g_ar,
    const int* __restrict__ q_mask, const int* __restrict__ k_mask,
    float2* __restrict__ pw, int* __restrict__ cnt, float* __restrict__ out)
{
    const int j  = blockIdx.x, i = blockIdx.y;
    const int sh = blockIdx.z >> 1, th = blockIdx.z & 1;
    const int tid  = threadIdx.x;
    const int w    = tid >> 6, lane = tid & 63;
    const int ln   = lane & 15, lg = lane >> 4;
    const int wsd  = w >> 1, wt = w & 1;     // wave's (s,t) quadrant

    __shared__ __align__(16) unsigned short As[128 * 64];  // 16 KB, swizzled
    __shared__ __align__(16) unsigned short Bs[128 * 64];  // 16 KB, swizzled
    __shared__ float w2[SEQ];     // scale * exp(-alpha*d)
    __shared__ float kmB[128];
    __shared__ float red[4];
    __shared__ int lastf;

    float a0 = g_ar[0];
    float alpha = (a0 > 0.f) ? a0 : 0.01f * a0;        // leaky_relu
    float scale = __expf(g_ls[0]);
    w2[tid] = scale * __expf(-alpha * (float)tid);
    if (tid < 128) kmB[tid] = (k_mask[j * SEQ + th * 128 + tid] != 0) ? 1.f : 0.f;

    // glds staging: lane covers row (base + lane>>3), swizzled source chunk
    const int rl  = lane >> 3;
    const int gch = (lane & 7) ^ rl;      // LDS chunk slot (lane&7) <- global chunk (lane&7)^(row&7)
    const unsigned short* aq = qn + ((size_t)i * SEQ + sh * 128 + w * 8 + rl) * HD + gch * 8;
    const unsigned short* bq = kn + ((size_t)j * SEQ + th * 128 + w * 8 + rl) * HD + gch * 8;
    unsigned short* al = As + (w * 8) * 64;
    unsigned short* bl = Bs + (w * 8) * 64;

    f32x4 acc[4][4];
    const f32x4 zero4 = {0.f, 0.f, 0.f, 0.f};
#pragma unroll
    for (int a = 0; a < 4; ++a)
#pragma unroll
        for (int b = 0; b < 4; ++b) acc[a][b] = zero4;

    for (int kk = 0; kk < HD; kk += 64) {
        __syncthreads();                       // prev stage consumed
#pragma unroll
        for (int c = 0; c < 4; ++c) {
            glds16(aq + kk + c * (32 * HD), al + c * (32 * 64));
            glds16(bq + kk + c * (32 * HD), bl + c * (32 * 64));
        }
        __syncthreads();                       // vmcnt drained before barrier
        const bf16x8* A8 = (const bf16x8*)As;
        const bf16x8* B8 = (const bf16x8*)Bs;
#pragma unroll
        for (int ks = 0; ks < 2; ++ks) {
            const int ch = (ks * 4 + lg) ^ (ln & 7);   // unswizzle
            bf16x8 af[4], bfr[4];
#pragma unroll
            for (int rm = 0; rm < 4; ++rm)
                af[rm] = A8[(wsd * 64 + rm * 16 + ln) * 8 + ch];
#pragma unroll
            for (int cn = 0; cn < 4; ++cn)
                bfr[cn] = B8[(wt * 64 + cn * 16 + ln) * 8 + ch];
#pragma unroll
            for (int rm = 0; rm < 4; ++rm)
#pragma unroll
                for (int cn = 0; cn < 4; ++cn)
                    acc[rm][cn] = __builtin_amdgcn_mfma_f32_16x16x32_bf16(
                        af[rm], bfr[cn], acc[rm][cn], 0, 0, 0);
        }
    }

    // epilogue: C/D layout col=ln (t), row=lg*4+r (s)
    __syncthreads();                    // all As/Bs reads done; reuse As as scratch
    float* zs  = (float*)As;            // [128][2] Z partials per (srow, wt)
    float* wsc = zs + 256;              // [128][2] W partials

#pragma unroll
    for (int rm = 0; rm < 4; ++rm)
#pragma unroll
        for (int r = 0; r < 4; ++r) {
            int srow = wsd * 64 + rm * 16 + lg * 4 + r;   // s within block's 128
            int s  = sh * 128 + srow;
            float ze = 0.f, we = 0.f;
#pragma unroll
            for (int cn = 0; cn < 4; ++cn) {
                int t = th * 128 + wt * 64 + cn * 16 + ln;
                float sim = acc[rm][cn][r];
                int d = s - t; d = (d < 0) ? -d : d;
                float e = kmB[wt * 64 + cn * 16 + ln] * __expf(sim * w2[d]);
                ze += e;
                we = fmaf(e, sim, we);
            }
#pragma unroll
            for (int m = 1; m < 16; m <<= 1) {            // reduce over t-16 lanes
                ze += __shfl_xor(ze, m, 64);
                we += __shfl_xor(we, m, 64);
            }
            if (ln == 0) { zs[srow * 2 + wt] = ze; wsc[srow * 2 + wt] = we; }
        }
    __syncthreads();

    // block-level (Z,W) per row -> pw[(pair*256 + s)*2 + th], coalesced float2
    const int pair = i * BK2 + j;
    if (tid < 128) {
        float Zb = zs[2 * tid] + zs[2 * tid + 1];
        float Wb = wsc[2 * tid] + wsc[2 * tid + 1];
        pw[((size_t)pair * SEQ + sh * 128 + tid) * 2 + th] = make_float2(Zb, Wb);
    }
    __threadfence();                           // release: partials visible device-wide
    if (tid == 0) lastf = (atomicAdd(&cnt[pair], 1) == 3);
    __syncthreads();
    if (!lastf) return;
    __threadfence();                           // acquire: see other blocks' partials

    // last block finishes: softmax divide, q-mask, reduce over s
    float4 p = ((const float4*)pw)[(size_t)pair * SEQ + tid];  // (Z0,W0,Z1,W1) row=tid
    float Z = p.x + p.z, W = p.y + p.w;
    float pt = (Z > 0.f) ? (W / Z) : 0.f;
    float part = pt * (float)q_mask[i * SEQ + tid];
#pragma unroll
    for (int m = 1; m < 64; m <<= 1) part += __shfl_xor(part, m, 64);
    if (lane == 0) red[w] = part;
    __syncthreads();
    if (tid == 0) out[pair] = red[0] + red[1] + red[2] + red[3];
}

extern "C" void kernel_launch(void* const* d_in, const int* in_sizes, int n_in,
                              void* d_out, int out_size, void* d_ws, size_t ws_size,
                              hipStream_t stream) {
    const float* q  = (const float*)d_in[0];   // [16,256,768] f32
    const float* k  = (const float*)d_in[1];   // [32,256,768] f32
    const float* ls = (const float*)d_in[2];   // scalar
    const float* ar = (const float*)d_in[3];   // scalar
    const int* qm   = (const int*)d_in[4];     // [16,256]
    const int* km   = (const int*)d_in[5];     // [32,256]
    float* out      = (float*)d_out;           // [16,32] f32

    unsigned short* qn = (unsigned short*)d_ws;            // 16*256*768 bf16
    unsigned short* kn = qn + (size_t)BQ * SEQ * HD;       // 32*256*768 bf16
    float2* pw = (float2*)(kn + (size_t)BK2 * SEQ * HD);   // 512*256*2 float2 = 2 MB
    int* cnt   = (int*)(pw + (size_t)BQ * BK2 * SEQ * 2);  // 512 ints

    norm_kernel<<<(BQ + BK2) * SEQ / 4, 256, 0, stream>>>(q, k, qn, kn, cnt);
    li_kernel<<<dim3(BK2, BQ, 4), 256, 0, stream>>>(qn, kn, ls, ar, qm, km, pw, cnt, (float*)d_out);
}

// Round 6
// 187.016 us; speedup vs baseline: 1.8330x; 1.8330x over previous
//
#include <hip/hip_runtime.h>
#include <hip/hip_bf16.h>

#define BQ   16
#define BK2  32     // 2B
#define SEQ  256
#define HD   768

typedef __attribute__((ext_vector_type(8))) short bf16x8;
typedef __attribute__((ext_vector_type(4))) float f32x4;

__device__ __forceinline__ void glds16(const unsigned short* g, unsigned short* l) {
    __builtin_amdgcn_global_load_lds(
        (const __attribute__((address_space(1))) unsigned int*)g,
        (__attribute__((address_space(3))) unsigned int*)l, 16, 0, 0);
}

// branch-free RNE fp32->bf16, packed two at a time
__device__ __forceinline__ unsigned int pack2_bf16(float a, float b) {
    unsigned ua = __float_as_uint(a), ub = __float_as_uint(b);
    ua += 0x7FFFu + ((ua >> 16) & 1u);
    ub += 0x7FFFu + ((ub >> 16) & 1u);
    return (ua >> 16) | (ub & 0xFFFF0000u);
}

// ---------------- Phase 1: fp32 l2-normalize -> bf16 (+ zero li scratch) ---
// blocks 0..255 also zero the 1 MB pwZ/pwW accumulators; block 0 zeroes cnt.
__global__ __launch_bounds__(256) void norm_kernel(
    const float* __restrict__ q, const float* __restrict__ k,
    unsigned short* __restrict__ qn, unsigned short* __restrict__ kn,
    float* __restrict__ pwzero, int* __restrict__ cnt)
{
    if (blockIdx.x < 256) {       // zero 256 blocks * 256 thr * 16 B = 1 MB
        ((float4*)pwzero)[blockIdx.x * 256 + threadIdx.x] =
            make_float4(0.f, 0.f, 0.f, 0.f);
        if (blockIdx.x == 0 && threadIdx.x < 128)
            ((int4*)cnt)[threadIdx.x] = make_int4(0, 0, 0, 0);
    }
    int row  = blockIdx.x * 4 + (threadIdx.x >> 6);
    int lane = threadIdx.x & 63;
    const int NQ = BQ * SEQ;
    const float* src = (row < NQ) ? q + (size_t)row * HD
                                  : k + (size_t)(row - NQ) * HD;
    unsigned int* dst = (unsigned int*)((row < NQ) ? qn + (size_t)row * HD
                                                   : kn + (size_t)(row - NQ) * HD);
    float4 v[3];
    float ss = 0.f;
#pragma unroll
    for (int c = 0; c < 3; ++c) {
        v[c] = ((const float4*)src)[lane + 64 * c];
        ss += v[c].x * v[c].x + v[c].y * v[c].y + v[c].z * v[c].z + v[c].w * v[c].w;
    }
#pragma unroll
    for (int m = 1; m < 64; m <<= 1) ss += __shfl_xor(ss, m, 64);
    float inv = rsqrtf(fmaxf(ss, 1e-24f));
#pragma unroll
    for (int c = 0; c < 3; ++c) {
        uint2 o = make_uint2(pack2_bf16(v[c].x * inv, v[c].y * inv),
                             pack2_bf16(v[c].z * inv, v[c].w * inv));
        ((uint2*)dst)[lane + 64 * c] = o;
    }
}

// ---------------- Phase 2: R2's proven shape: block = (j,i,sh|th), 128x128,
// 4 waves as 2x2 of 64x64 MFMA tiles, glds staging, swizzled LDS (pitch 64),
// 34.8 KB LDS -> 4 blocks/CU, grid 2048 = exactly 2 residency rounds.
// Tail: atomics-only cross-block combine (NO fences — R5 showed __threadfence
// write-through costs ~190 us). Last of 4 blocks per pair finishes inline.
__global__ __launch_bounds__(256, 4) void li_kernel(
    const unsigned short* __restrict__ qn, const unsigned short* __restrict__ kn,
    const float* __restrict__ g_ls, const float* __restrict__ g_ar,
    const int* __restrict__ q_mask, const int* __restrict__ k_mask,
    float* __restrict__ pwZ, float* __restrict__ pwW,
    int* __restrict__ cnt, float* __restrict__ out)
{
    const int j  = blockIdx.x, i = blockIdx.y;
    const int sh = blockIdx.z >> 1, th = blockIdx.z & 1;
    const int tid  = threadIdx.x;
    const int w    = tid >> 6, lane = tid & 63;
    const int ln   = lane & 15, lg = lane >> 4;
    const int wsd  = w >> 1, wt = w & 1;     // wave's (s,t) quadrant

    __shared__ __align__(16) unsigned short As[128 * 64];  // 16 KB, swizzled
    __shared__ __align__(16) unsigned short Bs[128 * 64];  // 16 KB, swizzled
    __shared__ float w2[SEQ];     // scale * exp(-alpha*d)
    __shared__ float kmB[128];
    __shared__ float red[4];
    __shared__ int lastf;

    float a0 = g_ar[0];
    float alpha = (a0 > 0.f) ? a0 : 0.01f * a0;        // leaky_relu
    float scale = __expf(g_ls[0]);
    w2[tid] = scale * __expf(-alpha * (float)tid);
    if (tid < 128) kmB[tid] = (k_mask[j * SEQ + th * 128 + tid] != 0) ? 1.f : 0.f;

    // glds staging: lane covers row (base + lane>>3), swizzled source chunk
    const int rl  = lane >> 3;
    const int gch = (lane & 7) ^ rl;      // LDS chunk slot (lane&7) <- global chunk (lane&7)^(row&7)
    const unsigned short* aq = qn + ((size_t)i * SEQ + sh * 128 + w * 8 + rl) * HD + gch * 8;
    const unsigned short* bq = kn + ((size_t)j * SEQ + th * 128 + w * 8 + rl) * HD + gch * 8;
    unsigned short* al = As + (w * 8) * 64;
    unsigned short* bl = Bs + (w * 8) * 64;

    f32x4 acc[4][4];
    const f32x4 zero4 = {0.f, 0.f, 0.f, 0.f};
#pragma unroll
    for (int a = 0; a < 4; ++a)
#pragma unroll
        for (int b = 0; b < 4; ++b) acc[a][b] = zero4;

    for (int kk = 0; kk < HD; kk += 64) {
        __syncthreads();                       // prev stage consumed
#pragma unroll
        for (int c = 0; c < 4; ++c) {
            glds16(aq + kk + c * (32 * HD), al + c * (32 * 64));
            glds16(bq + kk + c * (32 * HD), bl + c * (32 * 64));
        }
        __syncthreads();                       // vmcnt drained before barrier
        const bf16x8* A8 = (const bf16x8*)As;
        const bf16x8* B8 = (const bf16x8*)Bs;
#pragma unroll
        for (int ks = 0; ks < 2; ++ks) {
            const int ch = (ks * 4 + lg) ^ (ln & 7);   // unswizzle
            bf16x8 af[4], bfr[4];
#pragma unroll
            for (int rm = 0; rm < 4; ++rm)
                af[rm] = A8[(wsd * 64 + rm * 16 + ln) * 8 + ch];
#pragma unroll
            for (int cn = 0; cn < 4; ++cn)
                bfr[cn] = B8[(wt * 64 + cn * 16 + ln) * 8 + ch];
#pragma unroll
            for (int rm = 0; rm < 4; ++rm)
#pragma unroll
                for (int cn = 0; cn < 4; ++cn)
                    acc[rm][cn] = __builtin_amdgcn_mfma_f32_16x16x32_bf16(
                        af[rm], bfr[cn], acc[rm][cn], 0, 0, 0);
        }
    }

    // epilogue: C/D layout col=ln (t), row=lg*4+r (s)
    __syncthreads();                    // all As/Bs reads done; reuse As as scratch
    float* zs  = (float*)As;            // [128][2] Z partials per (srow, wt)
    float* wsc = zs + 256;              // [128][2] W partials

#pragma unroll
    for (int rm = 0; rm < 4; ++rm)
#pragma unroll
        for (int r = 0; r < 4; ++r) {
            int srow = wsd * 64 + rm * 16 + lg * 4 + r;   // s within block's 128
            int s  = sh * 128 + srow;
            float ze = 0.f, we = 0.f;
#pragma unroll
            for (int cn = 0; cn < 4; ++cn) {
                int t = th * 128 + wt * 64 + cn * 16 + ln;
                float sim = acc[rm][cn][r];
                int d = s - t; d = (d < 0) ? -d : d;
                float e = kmB[wt * 64 + cn * 16 + ln] * __expf(sim * w2[d]);
                ze += e;
                we = fmaf(e, sim, we);
            }
#pragma unroll
            for (int m = 1; m < 16; m <<= 1) {            // reduce over t-16 lanes
                ze += __shfl_xor(ze, m, 64);
                we += __shfl_xor(we, m, 64);
            }
            if (ln == 0) { zs[srow * 2 + wt] = ze; wsc[srow * 2 + wt] = we; }
        }
    __syncthreads();

    // block (Z,W) per row -> relaxed atomicAdd into pwZ/pwW (L2-coherent)
    const int pair = i * BK2 + j;
    if (tid < 128) {
        float Zb = zs[2 * tid] + zs[2 * tid + 1];
        float Wb = wsc[2 * tid] + wsc[2 * tid + 1];
        int srow = sh * 128 + tid;
        atomicAdd(&pwZ[pair * SEQ + srow], Zb);
        atomicAdd(&pwW[pair * SEQ + srow], Wb);
    }
    __syncthreads();
    // signal: ACQ_REL RMW orders this block's pw atomics before the count,
    // and gives the finisher acquire over the other blocks' atomics.
    if (tid == 0)
        lastf = (__hip_atomic_fetch_add(cnt + pair, 1, __ATOMIC_ACQ_REL,
                                        __HIP_MEMORY_SCOPE_AGENT) == 3);
    __syncthreads();
    if (!lastf) return;

    // last block finishes: L2-direct atomic loads (bypass stale vL1)
    float Z = __hip_atomic_load(pwZ + pair * SEQ + tid, __ATOMIC_RELAXED,
                                __HIP_MEMORY_SCOPE_AGENT);
    float W = __hip_atomic_load(pwW + pair * SEQ + tid, __ATOMIC_RELAXED,
                                __HIP_MEMORY_SCOPE_AGENT);
    float pt = (Z > 0.f) ? (W / Z) : 0.f;
    float part = pt * (float)q_mask[i * SEQ + tid];
#pragma unroll
    for (int m = 1; m < 64; m <<= 1) part += __shfl_xor(part, m, 64);
    if (lane == 0) red[w] = part;
    __syncthreads();
    if (tid == 0) out[pair] = red[0] + red[1] + red[2] + red[3];
}

extern "C" void kernel_launch(void* const* d_in, const int* in_sizes, int n_in,
                              void* d_out, int out_size, void* d_ws, size_t ws_size,
                              hipStream_t stream) {
    const float* q  = (const float*)d_in[0];   // [16,256,768] f32
    const float* k  = (const float*)d_in[1];   // [32,256,768] f32
    const float* ls = (const float*)d_in[2];   // scalar
    const float* ar = (const float*)d_in[3];   // scalar
    const int* qm   = (const int*)d_in[4];     // [16,256]
    const int* km   = (const int*)d_in[5];     // [32,256]
    float* out      = (float*)d_out;           // [16,32] f32

    unsigned short* qn = (unsigned short*)d_ws;            // 16*256*768 bf16
    unsigned short* kn = qn + (size_t)BQ * SEQ * HD;       // 32*256*768 bf16
    float* pwZ = (float*)(kn + (size_t)BK2 * SEQ * HD);    // 512*256 f32 (512 KB)
    float* pwW = pwZ + (size_t)BQ * BK2 * SEQ;             // 512*256 f32 (512 KB)
    int* cnt   = (int*)(pwW + (size_t)BQ * BK2 * SEQ);     // 512 ints

    norm_kernel<<<(BQ + BK2) * SEQ / 4, 256, 0, stream>>>(q, k, qn, kn, pwZ, cnt);
    li_kernel<<<dim3(BK2, BQ, 4), 256, 0, stream>>>(qn, kn, ls, ar, qm, km,
                                                    pwZ, pwW, cnt, (float*)d_out);
}

// Round 7
// 150.907 us; speedup vs baseline: 2.2716x; 1.2393x over previous
//
#include <hip/hip_runtime.h>
#include <hip/hip_bf16.h>

#define BQ   16
#define BK2  32     // 2B
#define SEQ  256
#define HD   768

typedef __attribute__((ext_vector_type(8))) short bf16x8;
typedef __attribute__((ext_vector_type(4))) float f32x4;

__device__ __forceinline__ void glds16(const unsigned short* g, unsigned short* l) {
    __builtin_amdgcn_global_load_lds(
        (const __attribute__((address_space(1))) unsigned int*)g,
        (__attribute__((address_space(3))) unsigned int*)l, 16, 0, 0);
}

// branch-free RNE fp32->bf16, packed two at a time
__device__ __forceinline__ unsigned int pack2_bf16(float a, float b) {
    unsigned ua = __float_as_uint(a), ub = __float_as_uint(b);
    ua += 0x7FFFu + ((ua >> 16) & 1u);
    ub += 0x7FFFu + ((ub >> 16) & 1u);
    return (ua >> 16) | (ub & 0xFFFF0000u);
}

// ---------------- Phase 1: fp32 l2-normalize -> bf16 (+ zero d_out) --------
__global__ __launch_bounds__(256) void norm_kernel(
    const float* __restrict__ q, const float* __restrict__ k,
    unsigned short* __restrict__ qn, unsigned short* __restrict__ kn,
    float* __restrict__ out)
{
    if (blockIdx.x == 0 && threadIdx.x < 256) {      // zero out for li's atomics
        out[threadIdx.x] = 0.f; out[threadIdx.x + 256] = 0.f;
    }
    int row  = blockIdx.x * 4 + (threadIdx.x >> 6);
    int lane = threadIdx.x & 63;
    const int NQ = BQ * SEQ;
    const float* src = (row < NQ) ? q + (size_t)row * HD
                                  : k + (size_t)(row - NQ) * HD;
    unsigned int* dst = (unsigned int*)((row < NQ) ? qn + (size_t)row * HD
                                                   : kn + (size_t)(row - NQ) * HD);
    float4 v[3];
    float ss = 0.f;
#pragma unroll
    for (int c = 0; c < 3; ++c) {
        v[c] = ((const float4*)src)[lane + 64 * c];
        ss += v[c].x * v[c].x + v[c].y * v[c].y + v[c].z * v[c].z + v[c].w * v[c].w;
    }
#pragma unroll
    for (int m = 1; m < 64; m <<= 1) ss += __shfl_xor(ss, m, 64);
    float inv = rsqrtf(fmaxf(ss, 1e-24f));
#pragma unroll
    for (int c = 0; c < 3; ++c) {
        uint2 o = make_uint2(pack2_bf16(v[c].x * inv, v[c].y * inv),
                             pack2_bf16(v[c].z * inv, v[c].w * inv));
        ((uint2*)dst)[lane + 64 * c] = o;
    }
}

// ---------------- Phase 2: block = (j, i, sh) covering 64 s x 256 t (full t)
// 4 waves = 4 t-quarters of 64x64 MFMA tiles. glds staging, swizzled LDS.
// LDS exactly 40960 B (As 8K + Bs 32K) -> 4 blocks/CU; all softmax state
// completes in-block; ONE fp32 atomicAdd per block (cross-XCD traffic is
// expensive on gfx950 — R5 fences / R6 data-atomics both regressed badly).
__global__ __launch_bounds__(256, 4) void li_kernel(
    const unsigned short* __restrict__ qn, const unsigned short* __restrict__ kn,
    const float* __restrict__ g_ls, const float* __restrict__ g_ar,
    const int* __restrict__ q_mask, const int* __restrict__ k_mask,
    float* __restrict__ out)
{
    const int j  = blockIdx.x, i = blockIdx.y, sh = blockIdx.z;
    const int tid  = threadIdx.x;
    const int w    = tid >> 6, lane = tid & 63;
    const int ln   = lane & 15, lg = lane >> 4;
    const int wt   = w;                       // wave's t-quarter

    __shared__ __align__(16) unsigned short As[64 * 64];   //  8 KB, swizzled
    __shared__ __align__(16) unsigned short Bs[256 * 64];  // 32 KB, swizzled
    // total LDS = 40960 B exactly -> 4 blocks/CU. No other __shared__;
    // epilogue scratch reuses the As region after a barrier.

    float a0 = g_ar[0];
    float alpha = (a0 > 0.f) ? a0 : 0.01f * a0;        // leaky_relu
    float scale = __expf(g_ls[0]);

    // glds staging: lane covers row (base + lane>>3), swizzled source chunk
    const int rl  = lane >> 3;
    const int gch = (lane & 7) ^ rl;      // LDS chunk slot (lane&7) <- global chunk (lane&7)^(row&7)
    const unsigned short* aq = qn + ((size_t)i * SEQ + sh * 64 + w * 8 + rl) * HD + gch * 8;
    const unsigned short* bq = kn + ((size_t)j * SEQ + w * 8 + rl) * HD + gch * 8;
    unsigned short* al = As + (w * 8) * 64;
    unsigned short* bl = Bs + (w * 8) * 64;

    f32x4 acc[4][4];
    const f32x4 zero4 = {0.f, 0.f, 0.f, 0.f};
#pragma unroll
    for (int a = 0; a < 4; ++a)
#pragma unroll
        for (int b = 0; b < 4; ++b) acc[a][b] = zero4;

    for (int kk = 0; kk < HD; kk += 64) {
        __syncthreads();                       // prev stage consumed
#pragma unroll
        for (int c = 0; c < 2; ++c)            // A rows 0..63 (32 rows/issue)
            glds16(aq + kk + c * (32 * HD), al + c * (32 * 64));
#pragma unroll
        for (int c = 0; c < 8; ++c)            // B rows 0..255
            glds16(bq + kk + c * (32 * HD), bl + c * (32 * 64));
        __syncthreads();                       // vmcnt drained before barrier
        const bf16x8* A8 = (const bf16x8*)As;
        const bf16x8* B8 = (const bf16x8*)Bs;
#pragma unroll
        for (int ks = 0; ks < 2; ++ks) {
            const int ch = (ks * 4 + lg) ^ (ln & 7);   // unswizzle
            bf16x8 af[4], bfr[4];
#pragma unroll
            for (int rm = 0; rm < 4; ++rm)
                af[rm] = A8[(rm * 16 + ln) * 8 + ch];
#pragma unroll
            for (int cn = 0; cn < 4; ++cn)
                bfr[cn] = B8[(wt * 64 + cn * 16 + ln) * 8 + ch];
#pragma unroll
            for (int rm = 0; rm < 4; ++rm)
#pragma unroll
                for (int cn = 0; cn < 4; ++cn)
                    acc[rm][cn] = __builtin_amdgcn_mfma_f32_16x16x32_bf16(
                        af[rm], bfr[cn], acc[rm][cn], 0, 0, 0);
        }
    }

    // k_mask for this lane's 4 t-columns (global, L2-hot; tables dropped to
    // keep LDS at 40960)
    float kmv[4];
#pragma unroll
    for (int cn = 0; cn < 4; ++cn)
        kmv[cn] = (k_mask[j * SEQ + wt * 64 + cn * 16 + ln] != 0) ? 1.f : 0.f;

    // epilogue: C/D layout col=ln (t), row=lg*4+r (s)
    __syncthreads();                    // all As/Bs reads done; reuse As as scratch
    float* zs  = (float*)As;            // [64][4] Z partials per (srow, wt)
    float* wsc = zs + 256;              // [64][4] W partials

#pragma unroll
    for (int rm = 0; rm < 4; ++rm)
#pragma unroll
        for (int r = 0; r < 4; ++r) {
            int srow = rm * 16 + lg * 4 + r;          // s within block's 64
            int s  = sh * 64 + srow;
            float ze = 0.f, we = 0.f;
#pragma unroll
            for (int cn = 0; cn < 4; ++cn) {
                int t = wt * 64 + cn * 16 + ln;       // global t (full 256 in-block)
                float sim = acc[rm][cn][r];
                int d = s - t; d = (d < 0) ? -d : d;
                float wd = __expf(-alpha * (float)d); // distance weight
                float e  = kmv[cn] * __expf(sim * scale * wd);
                ze += e;
                we = fmaf(e, sim, we);
            }
#pragma unroll
            for (int m = 1; m < 16; m <<= 1) {        // reduce over t-16 lanes
                ze += __shfl_xor(ze, m, 64);
                we += __shfl_xor(we, m, 64);
            }
            if (ln == 0) { zs[srow * 4 + wt] = ze; wsc[srow * 4 + wt] = we; }
        }
    __syncthreads();

    // wave 0 finishes: combine 4 wt-quarters, divide, q-mask, reduce 64 rows,
    // single atomicAdd into out[pair]
    if (w == 0) {
        const float4 Z4 = ((const float4*)zs)[lane];
        const float4 W4 = ((const float4*)wsc)[lane];
        float Z = Z4.x + Z4.y + Z4.z + Z4.w;
        float W = W4.x + W4.y + W4.z + W4.w;
        float pt = (Z > 0.f) ? (W / Z) : 0.f;
        float part = pt * (float)q_mask[i * SEQ + sh * 64 + lane];
#pragma unroll
        for (int m = 1; m < 64; m <<= 1) part += __shfl_xor(part, m, 64);
        if (lane == 0) atomicAdd(&out[i * BK2 + j], part);
    }
}

extern "C" void kernel_launch(void* const* d_in, const int* in_sizes, int n_in,
                              void* d_out, int out_size, void* d_ws, size_t ws_size,
                              hipStream_t stream) {
    const float* q  = (const float*)d_in[0];   // [16,256,768] f32
    const float* k  = (const float*)d_in[1];   // [32,256,768] f32
    const float* ls = (const float*)d_in[2];   // scalar
    const float* ar = (const float*)d_in[3];   // scalar
    const int* qm   = (const int*)d_in[4];     // [16,256]
    const int* km   = (const int*)d_in[5];     // [32,256]
    float* out      = (float*)d_out;           // [16,32] f32

    unsigned short* qn = (unsigned short*)d_ws;            // 16*256*768 bf16
    unsigned short* kn = qn + (size_t)BQ * SEQ * HD;       // 32*256*768 bf16

    norm_kernel<<<(BQ + BK2) * SEQ / 4, 256, 0, stream>>>(q, k, qn, kn, (float*)d_out);
    li_kernel<<<dim3(BK2, BQ, 4), 256, 0, stream>>>(qn, kn, ls, ar, qm, km, (float*)d_out);
}